// Round 7
// baseline (102.935 us; speedup 1.0000x reference)
//
#include <hip/hip_runtime.h>
#include <math.h>

#define DD_ 256
#define HH_ 512
#define OO_ 64

typedef __attribute__((ext_vector_type(8))) short bf16x8s;
typedef __attribute__((ext_vector_type(4))) short bf16x4s;
typedef __attribute__((ext_vector_type(4))) float f32x4;

__device__ __forceinline__ unsigned short f2bf(float f) {
    unsigned u = __float_as_uint(f);
    u += 0x7FFF + ((u >> 16) & 1);   // round-to-nearest-even
    return (unsigned short)(u >> 16);
}
__device__ __forceinline__ float bf2f(unsigned short h) {
    return __uint_as_float(((unsigned)h) << 16);
}
// XOR swizzle of the 16B slot within a 64B LDS row: 2-way-max bank aliasing
__device__ __forceinline__ int swz4(int r, int g) {
    return g ^ (r & 3) ^ ((r >> 2) & 3);
}

// ============ L1 mega-kernel: grid 512, uniform 2 blocks/CU ============
// every block: fused gemm1 + tanh + build Mt + b1/hd partials, then a 1/4
// slice of the Xt build (independent work, balances the grid).
__global__ __launch_bounds__(256) void k_mega(
    const float* __restrict__ x, const float* __restrict__ W1,
    const float* __restrict__ b1, const float* __restrict__ W2,
    const int* __restrict__ ap, const int* __restrict__ pI,
    const int* __restrict__ an, const int* __restrict__ nI,
    short* __restrict__ Mt, short* __restrict__ Xt,
    float* __restrict__ pb1, float* __restrict__ phd) {
    __shared__ short Ah[64 * 32], Al[64 * 32], Bh[64 * 32], Bl[64 * 32];
    __shared__ float ht[64][67];   // pad 67: pair-read stride 67 -> conflict-free
    __shared__ int sidx[64];
    const int t = threadIdx.x;
    const int bb = blockIdx.x;
    const int n0 = (bb & 7) * 64;
    const int ry = bb >> 3;
    const int s = ry >> 5;
    const int p0 = (ry & 31) * 32;
    const int* IA = s ? an : ap;
    const int* IB = s ? nI : pI;
    if (t < 32) sidx[t] = IA[p0 + t];
    else if (t < 64) sidx[t] = IB[p0 + t - 32];
    __syncthreads();
    const int row = t >> 2, q = t & 3;          // staging: row 0..63, 16B slot 0..3
    const int l = t & 63, w = t >> 6;
    const int wm = w >> 1, wn = w & 1;          // wave 2x2 over 64x64 tile
    const int lm = l & 15, g = l >> 4;          // frag: m/n = lm, k-slot = g
    const int sw = swz4(row, q);
    f32x4 acc[2][2] = {};
    for (int k0 = 0; k0 < DD_; k0 += 32) {
        {   // stage A: gathered x rows, fp32 -> bf16 hi/lo on the fly
            const float* src = x + (size_t)sidx[row] * DD_ + k0 + q * 8;
            float4 v0 = *(const float4*)src;
            float4 v1 = *(const float4*)(src + 4);
            float f[8] = {v0.x, v0.y, v0.z, v0.w, v1.x, v1.y, v1.z, v1.w};
            bf16x8s hi, lo;
            #pragma unroll
            for (int e = 0; e < 8; ++e) {
                unsigned short hh = f2bf(f[e]);
                hi[e] = (short)hh;
                lo[e] = (short)f2bf(f[e] - bf2f(hh));
            }
            *(bf16x8s*)(&Ah[(row * 4 + sw) * 8]) = hi;
            *(bf16x8s*)(&Al[(row * 4 + sw) * 8]) = lo;
        }
        {   // stage B: W1 rows, fp32 -> bf16 hi/lo on the fly
            const float* src = W1 + (size_t)(n0 + row) * DD_ + k0 + q * 8;
            float4 v0 = *(const float4*)src;
            float4 v1 = *(const float4*)(src + 4);
            float f[8] = {v0.x, v0.y, v0.z, v0.w, v1.x, v1.y, v1.z, v1.w};
            bf16x8s hi, lo;
            #pragma unroll
            for (int e = 0; e < 8; ++e) {
                unsigned short hh = f2bf(f[e]);
                hi[e] = (short)hh;
                lo[e] = (short)f2bf(f[e] - bf2f(hh));
            }
            *(bf16x8s*)(&Bh[(row * 4 + sw) * 8]) = hi;
            *(bf16x8s*)(&Bl[(row * 4 + sw) * 8]) = lo;
        }
        __syncthreads();
        bf16x8s ah[2], al[2], bh[2], bl[2];
        #pragma unroll
        for (int mi = 0; mi < 2; ++mi) {
            int r = wm * 32 + mi * 16 + lm;
            ah[mi] = *(const bf16x8s*)(&Ah[(r * 4 + swz4(r, g)) * 8]);
            al[mi] = *(const bf16x8s*)(&Al[(r * 4 + swz4(r, g)) * 8]);
        }
        #pragma unroll
        for (int nj = 0; nj < 2; ++nj) {
            int r = wn * 32 + nj * 16 + lm;
            bh[nj] = *(const bf16x8s*)(&Bh[(r * 4 + swz4(r, g)) * 8]);
            bl[nj] = *(const bf16x8s*)(&Bl[(r * 4 + swz4(r, g)) * 8]);
        }
        #pragma unroll
        for (int mi = 0; mi < 2; ++mi)
            #pragma unroll
            for (int nj = 0; nj < 2; ++nj) {
                acc[mi][nj] = __builtin_amdgcn_mfma_f32_16x16x32_bf16(ah[mi], bh[nj], acc[mi][nj], 0, 0, 0);
                acc[mi][nj] = __builtin_amdgcn_mfma_f32_16x16x32_bf16(ah[mi], bl[nj], acc[mi][nj], 0, 0, 0);
                acc[mi][nj] = __builtin_amdgcn_mfma_f32_16x16x32_bf16(al[mi], bh[nj], acc[mi][nj], 0, 0, 0);
            }
        __syncthreads();
    }
    // h-tile -> LDS (tanh applied); r<32 = a-side, r>=32 = b-side
    #pragma unroll
    for (int mi = 0; mi < 2; ++mi)
        #pragma unroll
        for (int nj = 0; nj < 2; ++nj) {
            int jl = wn * 32 + nj * 16 + lm;
            float bv = b1[n0 + jl];
            #pragma unroll
            for (int qq = 0; qq < 4; ++qq) {
                int r = wm * 32 + mi * 16 + g * 4 + qq;
                ht[r][jl] = tanhf(acc[mi][nj][qq] + bv);
            }
        }
    __syncthreads();
    // build M + partials: thread (il = t>>2, pq = t&3) handles 8 pairs of col il
    {
        const int il = t >> 2, pq = t & 3;
        float ci = 0.f;
        #pragma unroll 8
        for (int o = 0; o < OO_; ++o) { float wv = W2[o * HH_ + n0 + il]; ci += wv * wv; }
        const float sgn = s ? -1.f : 1.f;
        float b1p = 0.f, hdp = 0.f;
        bf16x8s v0, v1, v2;
        #pragma unroll
        for (int pp = 0; pp < 8; ++pp) {
            int pl = pq * 8 + pp;
            float ha = ht[pl][il];
            float hb = ht[pl + 32][il];
            float da = 1.f - ha * ha, db = 1.f - hb * hb;
            float s11 = sgn * (da * da * ci);
            float s12 = sgn * (-2.f * da * db * ci);
            float s22 = sgn * (db * db * ci);
            v0[pp] = (short)f2bf(s11);
            v1[pp] = (short)f2bf(s12);
            v2[pp] = (short)f2bf(s22);
            b1p += s11 + s12 + s22;
            float d = ha - hb;
            hdp += sgn * d * d;
        }
        size_t base = (size_t)(n0 + il) * 6144 + s * 1024 + p0 + pq * 8;
        *(bf16x8s*)(&Mt[base]) = v0;
        *(bf16x8s*)(&Mt[base + 2048]) = v1;
        *(bf16x8s*)(&Mt[base + 4096]) = v2;
        b1p += __shfl_xor(b1p, 1); b1p += __shfl_xor(b1p, 2);
        hdp += __shfl_xor(hdp, 1); hdp += __shfl_xor(hdp, 2);
        if (pq == 0) { pb1[ry * HH_ + n0 + il] = b1p; phd[ry * HH_ + n0 + il] = hdp; }
    }
    // ---- Xt quarter-slice: block also builds 1/4 of one Xt tile (64 j x 16 pairs)
    {
        const int xb = bb >> 2;              // 0..127
        const int quarter = bb & 3;          // 16-pair slice
        const int jblk = xb >> 5, pblk = xb & 31;
        const int j = jblk * 64 + (t >> 2);
        const int pq = t & 3;
        const int p0x = pblk * 64;           // global pair base incl. set
        const int sX = p0x >> 10;
        const int* IA2 = sX ? an : ap;
        const int* IB2 = sX ? nI : pI;
        const int pbase = (p0x & 1023) + quarter * 16 + pq * 4;
        short xv[3][4];
        #pragma unroll
        for (int pp = 0; pp < 4; ++pp) {
            int ia = IA2[pbase + pp];
            int ib = IB2[pbase + pp];
            float xa = x[(size_t)ia * DD_ + j];
            float xbv = x[(size_t)ib * DD_ + j];
            xv[0][pp] = (short)f2bf(xa * xa);
            xv[1][pp] = (short)f2bf(xa * xbv);
            xv[2][pp] = (short)f2bf(xbv * xbv);
        }
        size_t base = (size_t)j * 6144 + p0x + quarter * 16 + pq * 4;
        #pragma unroll
        for (int term = 0; term < 3; ++term) {
            bf16x4s v;
            #pragma unroll
            for (int e = 0; e < 4; ++e) v[e] = xv[term][e];
            *(bf16x4s*)(&Xt[base + (size_t)term * 2048]) = v;
        }
    }
}

// ============ L2: gemm2 + in-kernel split-K reduction (per-tile election) ====
// grid (4 jblk, 8 iblk, 16 kb); block(0,0,0) also writes b1d/W2d/b2d.
__global__ __launch_bounds__(256) void k_gemm2f(
    const short* __restrict__ Mt, const short* __restrict__ Xt,
    float* __restrict__ part, const float* __restrict__ pb1,
    const float* __restrict__ phd, float* __restrict__ out,
    int* __restrict__ counters) {
    __shared__ short As[64 * 32], Bs[64 * 32];
    __shared__ int elected;
    const int t = threadIdx.x;
    const int bx = blockIdx.x, by = blockIdx.y, kb = blockIdx.z;
    const int j0 = bx * 64;
    const int i0 = by * 64;
    const int HD = HH_ * DD_;   // 131072
    // small tail (depends only on mega output) in one early block
    if (bx == 0 && by == 0 && kb == 0) {
        const int i2 = t * 2;
        float s0 = 0.f, s1 = 0.f, h0 = 0.f, h1 = 0.f;
        for (int k2 = 0; k2 < 64; ++k2) {
            float2 pv = *(const float2*)(&pb1[k2 * HH_ + i2]);
            float2 hv = *(const float2*)(&phd[k2 * HH_ + i2]);
            s0 += pv.x; s1 += pv.y; h0 += hv.x; h1 += hv.y;
        }
        *(float2*)(&out[HD + i2]) = make_float2(s0, s1);
        float2 hb2 = make_float2(h0, h1);
        #pragma unroll 4
        for (int o = 0; o < OO_; ++o)
            *(float2*)(&out[HD + HH_ + o * HH_ + i2]) = hb2;
        if (t < OO_) out[HD + HH_ + OO_ * HH_ + t] = 0.f;
    }
    const int row = t >> 2, q = t & 3;
    const int l = t & 63, w = t >> 6;
    const int wm = w >> 1, wn = w & 1;
    const int lm = l & 15, g = l >> 4;
    const int sw = swz4(row, q);
    f32x4 acc[2][2] = {};
    for (int ks = 0; ks < 12; ++ks) {
        const int k0 = kb * 384 + ks * 32;
        *(bf16x8s*)(&As[(row * 4 + sw) * 8]) =
            *(const bf16x8s*)(&Mt[(size_t)(i0 + row) * 6144 + k0 + q * 8]);
        *(bf16x8s*)(&Bs[(row * 4 + sw) * 8]) =
            *(const bf16x8s*)(&Xt[(size_t)(j0 + row) * 6144 + k0 + q * 8]);
        __syncthreads();
        bf16x8s a[2], b[2];
        #pragma unroll
        for (int mi = 0; mi < 2; ++mi) {
            int r = wm * 32 + mi * 16 + lm;
            a[mi] = *(const bf16x8s*)(&As[(r * 4 + swz4(r, g)) * 8]);
        }
        #pragma unroll
        for (int nj = 0; nj < 2; ++nj) {
            int r = wn * 32 + nj * 16 + lm;
            b[nj] = *(const bf16x8s*)(&Bs[(r * 4 + swz4(r, g)) * 8]);
        }
        #pragma unroll
        for (int mi = 0; mi < 2; ++mi)
            #pragma unroll
            for (int nj = 0; nj < 2; ++nj)
                acc[mi][nj] = __builtin_amdgcn_mfma_f32_16x16x32_bf16(a[mi], b[nj], acc[mi][nj], 0, 0, 0);
        __syncthreads();
    }
    #pragma unroll
    for (int mi = 0; mi < 2; ++mi)
        #pragma unroll
        for (int nj = 0; nj < 2; ++nj) {
            int j = j0 + wn * 32 + nj * 16 + lm;
            #pragma unroll
            for (int qq = 0; qq < 4; ++qq) {
                int i = i0 + wm * 32 + mi * 16 + g * 4 + qq;
                part[((size_t)kb * HH_ + i) * DD_ + j] = acc[mi][nj][qq];
            }
        }
    // ---- election: last split-K block of this tile reduces kb=0..15 (fixed order)
    __threadfence();
    __syncthreads();
    if (t == 0) elected = (atomicAdd(&counters[by * 4 + bx], 1) == 15);
    __syncthreads();
    if (elected) {
        __threadfence();
        const int il = t >> 2;            // 0..63
        const int jc = (t & 3) * 16;      // 16 cols = 4 float4
        f32x4 sum[4] = {};
        for (int k2 = 0; k2 < 16; ++k2) {
            const float* p = &part[((size_t)k2 * HH_ + i0 + il) * DD_ + j0 + jc];
            #pragma unroll
            for (int cc = 0; cc < 4; ++cc) {
                f32x4 v = *(const f32x4*)(p + cc * 4);
                sum[cc] += v;
            }
        }
        float* o = &out[(size_t)(i0 + il) * DD_ + j0 + jc];
        #pragma unroll
        for (int cc = 0; cc < 4; ++cc)
            *(f32x4*)(o + cc * 4) = sum[cc];
    }
}

extern "C" void kernel_launch(void* const* d_in, const int* in_sizes, int n_in,
                              void* d_out, int out_size, void* d_ws, size_t ws_size,
                              hipStream_t stream) {
    const float* x  = (const float*)d_in[0];
    const float* W1 = (const float*)d_in[1];
    const float* b1 = (const float*)d_in[2];
    const float* W2 = (const float*)d_in[3];
    // d_in[4] = b2 (unused: b2 Jacobians cancel)
    const int* ap = (const int*)d_in[5];
    const int* pI = (const int*)d_in[6];
    const int* an = (const int*)d_in[7];
    const int* nI = (const int*)d_in[8];
    float* out = (float*)d_out;
    float* ws = (float*)d_ws;

    // workspace (float units)
    float* part = ws;                         // 16*131072 = 2097152
    short* Mt   = (short*)(ws + 2097152);     // 512*6144 shorts = 1572864 floats
    short* Xt   = (short*)(ws + 3670016);     // 256*6144 shorts =  786432 floats
    float* pb1  = ws + 4456448;               // 64*512 = 32768
    float* phd  = ws + 4489216;               // 64*512 = 32768
    int* counters = (int*)(ws + 4521984);     // 32 ints

    hipMemsetAsync(counters, 0, 32 * sizeof(int), stream);
    k_mega<<<dim3(512), dim3(256), 0, stream>>>(x, W1, b1, W2, ap, pI, an, nI,
                                                Mt, Xt, pb1, phd);
    k_gemm2f<<<dim3(4, 8, 16), dim3(256), 0, stream>>>(Mt, Xt, part, pb1, phd,
                                                       out, counters);
}

// Round 8
// 40.027 us; speedup vs baseline: 2.5717x; 2.5717x over previous
//
#include <hip/hip_runtime.h>
#include <math.h>

#define DD_ 256
#define HH_ 512
#define OO_ 64

typedef __attribute__((ext_vector_type(8))) short bf16x8s;
typedef __attribute__((ext_vector_type(4))) short bf16x4s;
typedef __attribute__((ext_vector_type(4))) float f32x4;

__device__ __forceinline__ unsigned short f2bf(float f) {
    unsigned u = __float_as_uint(f);
    u += 0x7FFF + ((u >> 16) & 1);   // round-to-nearest-even
    return (unsigned short)(u >> 16);
}
__device__ __forceinline__ float bf2f(unsigned short h) {
    return __uint_as_float(((unsigned)h) << 16);
}
// XOR swizzle of the 16B slot within a 64B LDS row: 2-way-max bank aliasing
__device__ __forceinline__ int swz4(int r, int g) {
    return g ^ (r & 3) ^ ((r >> 2) & 3);
}

// ============ L1 mega-kernel: grid 512, uniform 2 blocks/CU ============
// every block: zero its out slice, fused gemm1 + tanh + build Mt + b1/hd
// partials, then a 1/4 slice of the Xt build.
__global__ __launch_bounds__(256) void k_mega(
    const float* __restrict__ x, const float* __restrict__ W1,
    const float* __restrict__ b1, const float* __restrict__ W2,
    const int* __restrict__ ap, const int* __restrict__ pI,
    const int* __restrict__ an, const int* __restrict__ nI,
    short* __restrict__ Mt, short* __restrict__ Xt,
    float* __restrict__ pb1, float* __restrict__ phd,
    float* __restrict__ out) {
    __shared__ short Ah[64 * 32], Al[64 * 32], Bh[64 * 32], Bl[64 * 32];
    __shared__ float ht[64][67];   // pad 67: pair-read stride 67 -> conflict-free
    __shared__ int sidx[64];
    const int t = threadIdx.x;
    const int bb = blockIdx.x;
    out[bb * 256 + t] = 0.f;       // zero W1d region; gemm2 atomic-accumulates later
    const int n0 = (bb & 7) * 64;
    const int ry = bb >> 3;
    const int s = ry >> 5;
    const int p0 = (ry & 31) * 32;
    const int* IA = s ? an : ap;
    const int* IB = s ? nI : pI;
    if (t < 32) sidx[t] = IA[p0 + t];
    else if (t < 64) sidx[t] = IB[p0 + t - 32];
    __syncthreads();
    const int row = t >> 2, q = t & 3;          // staging: row 0..63, 16B slot 0..3
    const int l = t & 63, w = t >> 6;
    const int wm = w >> 1, wn = w & 1;          // wave 2x2 over 64x64 tile
    const int lm = l & 15, g = l >> 4;          // frag: m/n = lm, k-slot = g
    const int sw = swz4(row, q);
    f32x4 acc[2][2] = {};
    for (int k0 = 0; k0 < DD_; k0 += 32) {
        {   // stage A: gathered x rows, fp32 -> bf16 hi/lo on the fly
            const float* src = x + (size_t)sidx[row] * DD_ + k0 + q * 8;
            float4 v0 = *(const float4*)src;
            float4 v1 = *(const float4*)(src + 4);
            float f[8] = {v0.x, v0.y, v0.z, v0.w, v1.x, v1.y, v1.z, v1.w};
            bf16x8s hi, lo;
            #pragma unroll
            for (int e = 0; e < 8; ++e) {
                unsigned short hh = f2bf(f[e]);
                hi[e] = (short)hh;
                lo[e] = (short)f2bf(f[e] - bf2f(hh));
            }
            *(bf16x8s*)(&Ah[(row * 4 + sw) * 8]) = hi;
            *(bf16x8s*)(&Al[(row * 4 + sw) * 8]) = lo;
        }
        {   // stage B: W1 rows, fp32 -> bf16 hi/lo on the fly
            const float* src = W1 + (size_t)(n0 + row) * DD_ + k0 + q * 8;
            float4 v0 = *(const float4*)src;
            float4 v1 = *(const float4*)(src + 4);
            float f[8] = {v0.x, v0.y, v0.z, v0.w, v1.x, v1.y, v1.z, v1.w};
            bf16x8s hi, lo;
            #pragma unroll
            for (int e = 0; e < 8; ++e) {
                unsigned short hh = f2bf(f[e]);
                hi[e] = (short)hh;
                lo[e] = (short)f2bf(f[e] - bf2f(hh));
            }
            *(bf16x8s*)(&Bh[(row * 4 + sw) * 8]) = hi;
            *(bf16x8s*)(&Bl[(row * 4 + sw) * 8]) = lo;
        }
        __syncthreads();
        bf16x8s ah[2], al[2], bh[2], bl[2];
        #pragma unroll
        for (int mi = 0; mi < 2; ++mi) {
            int r = wm * 32 + mi * 16 + lm;
            ah[mi] = *(const bf16x8s*)(&Ah[(r * 4 + swz4(r, g)) * 8]);
            al[mi] = *(const bf16x8s*)(&Al[(r * 4 + swz4(r, g)) * 8]);
        }
        #pragma unroll
        for (int nj = 0; nj < 2; ++nj) {
            int r = wn * 32 + nj * 16 + lm;
            bh[nj] = *(const bf16x8s*)(&Bh[(r * 4 + swz4(r, g)) * 8]);
            bl[nj] = *(const bf16x8s*)(&Bl[(r * 4 + swz4(r, g)) * 8]);
        }
        #pragma unroll
        for (int mi = 0; mi < 2; ++mi)
            #pragma unroll
            for (int nj = 0; nj < 2; ++nj) {
                acc[mi][nj] = __builtin_amdgcn_mfma_f32_16x16x32_bf16(ah[mi], bh[nj], acc[mi][nj], 0, 0, 0);
                acc[mi][nj] = __builtin_amdgcn_mfma_f32_16x16x32_bf16(ah[mi], bl[nj], acc[mi][nj], 0, 0, 0);
                acc[mi][nj] = __builtin_amdgcn_mfma_f32_16x16x32_bf16(al[mi], bh[nj], acc[mi][nj], 0, 0, 0);
            }
        __syncthreads();
    }
    // h-tile -> LDS (tanh applied); r<32 = a-side, r>=32 = b-side
    #pragma unroll
    for (int mi = 0; mi < 2; ++mi)
        #pragma unroll
        for (int nj = 0; nj < 2; ++nj) {
            int jl = wn * 32 + nj * 16 + lm;
            float bv = b1[n0 + jl];
            #pragma unroll
            for (int qq = 0; qq < 4; ++qq) {
                int r = wm * 32 + mi * 16 + g * 4 + qq;
                ht[r][jl] = tanhf(acc[mi][nj][qq] + bv);
            }
        }
    __syncthreads();
    // build M + partials: thread (il = t>>2, pq = t&3) handles 8 pairs of col il
    {
        const int il = t >> 2, pq = t & 3;
        float ci = 0.f;
        #pragma unroll 8
        for (int o = 0; o < OO_; ++o) { float wv = W2[o * HH_ + n0 + il]; ci += wv * wv; }
        const float sgn = s ? -1.f : 1.f;
        float b1p = 0.f, hdp = 0.f;
        bf16x8s v0, v1, v2;
        #pragma unroll
        for (int pp = 0; pp < 8; ++pp) {
            int pl = pq * 8 + pp;
            float ha = ht[pl][il];
            float hb = ht[pl + 32][il];
            float da = 1.f - ha * ha, db = 1.f - hb * hb;
            float s11 = sgn * (da * da * ci);
            float s12 = sgn * (-2.f * da * db * ci);
            float s22 = sgn * (db * db * ci);
            v0[pp] = (short)f2bf(s11);
            v1[pp] = (short)f2bf(s12);
            v2[pp] = (short)f2bf(s22);
            b1p += s11 + s12 + s22;
            float d = ha - hb;
            hdp += sgn * d * d;
        }
        size_t base = (size_t)(n0 + il) * 6144 + s * 1024 + p0 + pq * 8;
        *(bf16x8s*)(&Mt[base]) = v0;
        *(bf16x8s*)(&Mt[base + 2048]) = v1;
        *(bf16x8s*)(&Mt[base + 4096]) = v2;
        b1p += __shfl_xor(b1p, 1); b1p += __shfl_xor(b1p, 2);
        hdp += __shfl_xor(hdp, 1); hdp += __shfl_xor(hdp, 2);
        if (pq == 0) { pb1[ry * HH_ + n0 + il] = b1p; phd[ry * HH_ + n0 + il] = hdp; }
    }
    // ---- Xt quarter-slice: block also builds 1/4 of one Xt tile (64 j x 16 pairs)
    {
        const int xb = bb >> 2;              // 0..127
        const int quarter = bb & 3;          // 16-pair slice
        const int jblk = xb >> 5, pblk = xb & 31;
        const int j = jblk * 64 + (t >> 2);
        const int pq = t & 3;
        const int p0x = pblk * 64;           // global pair base incl. set
        const int sX = p0x >> 10;
        const int* IA2 = sX ? an : ap;
        const int* IB2 = sX ? nI : pI;
        const int pbase = (p0x & 1023) + quarter * 16 + pq * 4;
        short xv[3][4];
        #pragma unroll
        for (int pp = 0; pp < 4; ++pp) {
            int ia = IA2[pbase + pp];
            int ib = IB2[pbase + pp];
            float xa = x[(size_t)ia * DD_ + j];
            float xbv = x[(size_t)ib * DD_ + j];
            xv[0][pp] = (short)f2bf(xa * xa);
            xv[1][pp] = (short)f2bf(xa * xbv);
            xv[2][pp] = (short)f2bf(xbv * xbv);
        }
        size_t base = (size_t)j * 6144 + p0x + quarter * 16 + pq * 4;
        #pragma unroll
        for (int term = 0; term < 3; ++term) {
            bf16x4s v;
            #pragma unroll
            for (int e = 0; e < 4; ++e) v[e] = xv[term][e];
            *(bf16x4s*)(&Xt[base + (size_t)term * 2048]) = v;
        }
    }
}

// ============ L2: gemm2, atomic-accumulate into out (no part, no fence) ====
// grid (4 jblk, 8 iblk, 16 kb); blocks (0,0,kb) also write tail pieces.
__global__ __launch_bounds__(256) void k_gemm2a(
    const short* __restrict__ Mt, const short* __restrict__ Xt,
    const float* __restrict__ pb1, const float* __restrict__ phd,
    float* __restrict__ out) {
    __shared__ short As[64 * 32], Bs[64 * 32];
    const int t = threadIdx.x;
    const int bx = blockIdx.x, by = blockIdx.y, kb = blockIdx.z;
    const int j0 = bx * 64;
    const int i0 = by * 64;
    const int HD = HH_ * DD_;   // 131072
    // tail pieces (depend only on mega output; stream-ordered, fence-free)
    if (bx == 0 && by == 0) {
        const int i2 = t * 2;
        float h0 = 0.f, h1 = 0.f;
        for (int k2 = 0; k2 < 64; ++k2) {
            float2 hv = *(const float2*)(&phd[k2 * HH_ + i2]);
            h0 += hv.x; h1 += hv.y;
        }
        float2 hb2 = make_float2(h0, h1);
        #pragma unroll
        for (int r = 0; r < 4; ++r)   // W2d rows kb*4 .. kb*4+3
            *(float2*)(&out[HD + HH_ + (kb * 4 + r) * HH_ + i2]) = hb2;
        if (kb == 0) {
            float s0 = 0.f, s1 = 0.f;
            for (int k2 = 0; k2 < 64; ++k2) {
                float2 pv = *(const float2*)(&pb1[k2 * HH_ + i2]);
                s0 += pv.x; s1 += pv.y;
            }
            *(float2*)(&out[HD + i2]) = make_float2(s0, s1);
            if (t < OO_) out[HD + HH_ + OO_ * HH_ + t] = 0.f;   // b2d
        }
    }
    const int row = t >> 2, q = t & 3;
    const int l = t & 63, w = t >> 6;
    const int wm = w >> 1, wn = w & 1;
    const int lm = l & 15, g = l >> 4;
    const int sw = swz4(row, q);
    f32x4 acc[2][2] = {};
    for (int ks = 0; ks < 12; ++ks) {
        const int k0 = kb * 384 + ks * 32;
        *(bf16x8s*)(&As[(row * 4 + sw) * 8]) =
            *(const bf16x8s*)(&Mt[(size_t)(i0 + row) * 6144 + k0 + q * 8]);
        *(bf16x8s*)(&Bs[(row * 4 + sw) * 8]) =
            *(const bf16x8s*)(&Xt[(size_t)(j0 + row) * 6144 + k0 + q * 8]);
        __syncthreads();
        bf16x8s a[2], b[2];
        #pragma unroll
        for (int mi = 0; mi < 2; ++mi) {
            int r = wm * 32 + mi * 16 + lm;
            a[mi] = *(const bf16x8s*)(&As[(r * 4 + swz4(r, g)) * 8]);
        }
        #pragma unroll
        for (int nj = 0; nj < 2; ++nj) {
            int r = wn * 32 + nj * 16 + lm;
            b[nj] = *(const bf16x8s*)(&Bs[(r * 4 + swz4(r, g)) * 8]);
        }
        #pragma unroll
        for (int mi = 0; mi < 2; ++mi)
            #pragma unroll
            for (int nj = 0; nj < 2; ++nj)
                acc[mi][nj] = __builtin_amdgcn_mfma_f32_16x16x32_bf16(a[mi], b[nj], acc[mi][nj], 0, 0, 0);
        __syncthreads();
    }
    #pragma unroll
    for (int mi = 0; mi < 2; ++mi)
        #pragma unroll
        for (int nj = 0; nj < 2; ++nj) {
            int j = j0 + wn * 32 + nj * 16 + lm;
            #pragma unroll
            for (int qq = 0; qq < 4; ++qq) {
                int i = i0 + wm * 32 + mi * 16 + g * 4 + qq;
                unsafeAtomicAdd(&out[(size_t)i * DD_ + j], acc[mi][nj][qq]);
            }
        }
}

extern "C" void kernel_launch(void* const* d_in, const int* in_sizes, int n_in,
                              void* d_out, int out_size, void* d_ws, size_t ws_size,
                              hipStream_t stream) {
    const float* x  = (const float*)d_in[0];
    const float* W1 = (const float*)d_in[1];
    const float* b1 = (const float*)d_in[2];
    const float* W2 = (const float*)d_in[3];
    // d_in[4] = b2 (unused: b2 Jacobians cancel)
    const int* ap = (const int*)d_in[5];
    const int* pI = (const int*)d_in[6];
    const int* an = (const int*)d_in[7];
    const int* nI = (const int*)d_in[8];
    float* out = (float*)d_out;
    float* ws = (float*)d_ws;

    // workspace (float units)
    short* Mt   = (short*)ws;                 // 512*6144 shorts = 1572864 floats
    short* Xt   = (short*)(ws + 1572864);     // 256*6144 shorts =  786432 floats
    float* pb1  = ws + 2359296;               // 64*512 = 32768
    float* phd  = ws + 2392064;               // 64*512 = 32768

    k_mega<<<dim3(512), dim3(256), 0, stream>>>(x, W1, b1, W2, ap, pI, an, nI,
                                                Mt, Xt, pb1, phd, out);
    k_gemm2a<<<dim3(4, 8, 16), dim3(256), 0, stream>>>(Mt, Xt, pb1, phd, out);
}

// Round 9
// 33.811 us; speedup vs baseline: 3.0444x; 1.1838x over previous
//
#include <hip/hip_runtime.h>
#include <math.h>

#define DD_ 256
#define HH_ 512
#define OO_ 64

typedef __attribute__((ext_vector_type(8))) short bf16x8s;
typedef __attribute__((ext_vector_type(4))) float f32x4;

__device__ __forceinline__ unsigned short f2bf(float f) {
    unsigned u = __float_as_uint(f);
    u += 0x7FFF + ((u >> 16) & 1);   // round-to-nearest-even
    return (unsigned short)(u >> 16);
}
__device__ __forceinline__ float bf2f(unsigned short h) {
    return __uint_as_float(((unsigned)h) << 16);
}
// XOR swizzle of the 16B slot within a 64B LDS row: 2-way-max bank aliasing
__device__ __forceinline__ int swz4(int r, int g) {
    return g ^ (r & 3) ^ ((r >> 2) & 3);
}
// tanh via v_exp_f32: ~6 instr vs ~25 for libm tanhf; |err| ~1e-6
__device__ __forceinline__ float fast_tanh(float z) {
    float e = __expf(2.f * z);           // inf for large z -> returns 1; 0 -> -1
    return 1.f - __fdividef(2.f, e + 1.f);
}

// ============ L1 mega-kernel: grid 640 ============
// bb < 512: fused gemm1 (reg-prefetched) + tanh + build Mt + b1/hd partials.
// bb >= 512: build Xt[256][6144] bf16 (independent work, same launch).
__global__ __launch_bounds__(256) void k_mega(
    const float* __restrict__ x, const float* __restrict__ W1,
    const float* __restrict__ b1, const float* __restrict__ W2,
    const int* __restrict__ ap, const int* __restrict__ pI,
    const int* __restrict__ an, const int* __restrict__ nI,
    short* __restrict__ Mt, short* __restrict__ Xt,
    float* __restrict__ pb1, float* __restrict__ phd) {
    const int t = threadIdx.x;
    const int bb = blockIdx.x;
    if (bb < 512) {
        __shared__ short Ah[64 * 32], Al[64 * 32], Bh[64 * 32], Bl[64 * 32];
        __shared__ float ht[64][67];   // pad 67: pair-read stride conflict-free
        __shared__ int sidx[64];
        const int n0 = (bb & 7) * 64;
        const int ry = bb >> 3;
        const int s = ry >> 5;
        const int p0 = (ry & 31) * 32;
        const int* IA = s ? an : ap;
        const int* IB = s ? nI : pI;
        if (t < 32) sidx[t] = IA[p0 + t];
        else if (t < 64) sidx[t] = IB[p0 + t - 32];
        __syncthreads();
        const int row = t >> 2, q = t & 3;          // staging: row 0..63, 16B slot
        const int l = t & 63, w = t >> 6;
        const int wm = w >> 1, wn = w & 1;          // wave 2x2 over 64x64 tile
        const int lm = l & 15, g = l >> 4;          // frag: m/n = lm, k-slot = g
        const int sw = swz4(row, q);
        const float* srcA = x + (size_t)sidx[row] * DD_ + q * 8;
        const float* srcB = W1 + (size_t)(n0 + row) * DD_ + q * 8;
        // prefetch k0=0
        float4 pa0 = *(const float4*)srcA;
        float4 pa1 = *(const float4*)(srcA + 4);
        float4 pb0 = *(const float4*)srcB;
        float4 pb1v = *(const float4*)(srcB + 4);
        f32x4 acc[2][2] = {};
        for (int k0 = 0; k0 < DD_; k0 += 32) {
            {   // convert prefetched A (gathered x): fp32 -> bf16 hi/lo
                float f[8] = {pa0.x, pa0.y, pa0.z, pa0.w, pa1.x, pa1.y, pa1.z, pa1.w};
                bf16x8s hi, lo;
                #pragma unroll
                for (int e = 0; e < 8; ++e) {
                    unsigned short hh = f2bf(f[e]);
                    hi[e] = (short)hh;
                    lo[e] = (short)f2bf(f[e] - bf2f(hh));
                }
                *(bf16x8s*)(&Ah[(row * 4 + sw) * 8]) = hi;
                *(bf16x8s*)(&Al[(row * 4 + sw) * 8]) = lo;
            }
            {   // convert prefetched B (W1 rows)
                float f[8] = {pb0.x, pb0.y, pb0.z, pb0.w, pb1v.x, pb1v.y, pb1v.z, pb1v.w};
                bf16x8s hi, lo;
                #pragma unroll
                for (int e = 0; e < 8; ++e) {
                    unsigned short hh = f2bf(f[e]);
                    hi[e] = (short)hh;
                    lo[e] = (short)f2bf(f[e] - bf2f(hh));
                }
                *(bf16x8s*)(&Bh[(row * 4 + sw) * 8]) = hi;
                *(bf16x8s*)(&Bl[(row * 4 + sw) * 8]) = lo;
            }
            __syncthreads();
            if (k0 + 32 < DD_) {   // issue next-step loads; complete under MFMA
                pa0 = *(const float4*)(srcA + k0 + 32);
                pa1 = *(const float4*)(srcA + k0 + 36);
                pb0 = *(const float4*)(srcB + k0 + 32);
                pb1v = *(const float4*)(srcB + k0 + 36);
            }
            bf16x8s ah[2], al[2], bh[2], bl[2];
            #pragma unroll
            for (int mi = 0; mi < 2; ++mi) {
                int r = wm * 32 + mi * 16 + lm;
                ah[mi] = *(const bf16x8s*)(&Ah[(r * 4 + swz4(r, g)) * 8]);
                al[mi] = *(const bf16x8s*)(&Al[(r * 4 + swz4(r, g)) * 8]);
            }
            #pragma unroll
            for (int nj = 0; nj < 2; ++nj) {
                int r = wn * 32 + nj * 16 + lm;
                bh[nj] = *(const bf16x8s*)(&Bh[(r * 4 + swz4(r, g)) * 8]);
                bl[nj] = *(const bf16x8s*)(&Bl[(r * 4 + swz4(r, g)) * 8]);
            }
            #pragma unroll
            for (int mi = 0; mi < 2; ++mi)
                #pragma unroll
                for (int nj = 0; nj < 2; ++nj) {
                    acc[mi][nj] = __builtin_amdgcn_mfma_f32_16x16x32_bf16(ah[mi], bh[nj], acc[mi][nj], 0, 0, 0);
                    acc[mi][nj] = __builtin_amdgcn_mfma_f32_16x16x32_bf16(ah[mi], bl[nj], acc[mi][nj], 0, 0, 0);
                    acc[mi][nj] = __builtin_amdgcn_mfma_f32_16x16x32_bf16(al[mi], bh[nj], acc[mi][nj], 0, 0, 0);
                }
            __syncthreads();
        }
        // h-tile -> LDS (tanh applied); r<32 = a-side, r>=32 = b-side
        #pragma unroll
        for (int mi = 0; mi < 2; ++mi)
            #pragma unroll
            for (int nj = 0; nj < 2; ++nj) {
                int jl = wn * 32 + nj * 16 + lm;
                float bv = b1[n0 + jl];
                #pragma unroll
                for (int qq = 0; qq < 4; ++qq) {
                    int r = wm * 32 + mi * 16 + g * 4 + qq;
                    ht[r][jl] = fast_tanh(acc[mi][nj][qq] + bv);
                }
            }
        __syncthreads();
        // build M + partials: thread (il = t>>2, pq = t&3) handles 8 pairs of col il
        const int il = t >> 2, pq = t & 3;
        float ci = 0.f;
        #pragma unroll 8
        for (int o = 0; o < OO_; ++o) { float wv = W2[o * HH_ + n0 + il]; ci += wv * wv; }
        const float sgn = s ? -1.f : 1.f;
        float b1p = 0.f, hdp = 0.f;
        bf16x8s v0, v1, v2;
        #pragma unroll
        for (int pp = 0; pp < 8; ++pp) {
            int pl = pq * 8 + pp;
            float ha = ht[pl][il];
            float hb = ht[pl + 32][il];
            float da = 1.f - ha * ha, db = 1.f - hb * hb;
            float s11 = sgn * (da * da * ci);
            float s12 = sgn * (-2.f * da * db * ci);
            float s22 = sgn * (db * db * ci);
            v0[pp] = (short)f2bf(s11);
            v1[pp] = (short)f2bf(s12);
            v2[pp] = (short)f2bf(s22);
            b1p += s11 + s12 + s22;
            float d = ha - hb;
            hdp += sgn * d * d;
        }
        size_t base = (size_t)(n0 + il) * 6144 + s * 1024 + p0 + pq * 8;
        *(bf16x8s*)(&Mt[base]) = v0;
        *(bf16x8s*)(&Mt[base + 2048]) = v1;
        *(bf16x8s*)(&Mt[base + 4096]) = v2;
        b1p += __shfl_xor(b1p, 1); b1p += __shfl_xor(b1p, 2);
        hdp += __shfl_xor(hdp, 1); hdp += __shfl_xor(hdp, 2);
        if (pq == 0) { pb1[ry * HH_ + n0 + il] = b1p; phd[ry * HH_ + n0 + il] = hdp; }
    } else {
        __shared__ int sia[64], sib[64];
        const int b2 = bb - 512;
        const int jblk = b2 >> 5, pblk = b2 & 31;
        const int j = jblk * 64 + (t >> 2), pq = t & 3;
        const int p0 = pblk * 64;
        const int s = p0 >> 10;
        const int* IA = s ? an : ap;
        const int* IB = s ? nI : pI;
        if (t < 64) sia[t] = IA[(p0 & 1023) + t];
        else if (t < 128) sib[t - 64] = IB[(p0 & 1023) + (t - 64)];
        __syncthreads();
        short xv[3][16];
        #pragma unroll
        for (int pp = 0; pp < 16; ++pp) {
            int pl = pq * 16 + pp;
            float xa = x[(size_t)sia[pl] * DD_ + j];
            float xb = x[(size_t)sib[pl] * DD_ + j];
            xv[0][pp] = (short)f2bf(xa * xa);
            xv[1][pp] = (short)f2bf(xa * xb);
            xv[2][pp] = (short)f2bf(xb * xb);
        }
        size_t base = (size_t)j * 6144 + p0 + pq * 16;
        #pragma unroll
        for (int term = 0; term < 3; ++term) {
            bf16x8s v0, v1;
            #pragma unroll
            for (int e = 0; e < 8; ++e) { v0[e] = xv[term][e]; v1[e] = xv[term][e + 8]; }
            *(bf16x8s*)(&Xt[base + (size_t)term * 2048]) = v0;
            *(bf16x8s*)(&Xt[base + (size_t)term * 2048 + 8]) = v1;
        }
    }
}

// ============ L2: part[kb][i][j] = sum_{k chunk 384} Mt[i][k]*Xt[j][k] ====
// grid (4 jblk, 8 iblk, 16 kb); reg-prefetched staging.
__global__ __launch_bounds__(256) void k_gemm2(
    const short* __restrict__ Mt, const short* __restrict__ Xt,
    float* __restrict__ part) {
    __shared__ short As[64 * 32], Bs[64 * 32];
    const int t = threadIdx.x;
    const int j0 = blockIdx.x * 64;
    const int i0 = blockIdx.y * 64;
    const int kb = blockIdx.z;
    const int row = t >> 2, q = t & 3;
    const int l = t & 63, w = t >> 6;
    const int wm = w >> 1, wn = w & 1;
    const int lm = l & 15, g = l >> 4;
    const int sw = swz4(row, q);
    const short* srcA = &Mt[(size_t)(i0 + row) * 6144 + kb * 384 + q * 8];
    const short* srcB = &Xt[(size_t)(j0 + row) * 6144 + kb * 384 + q * 8];
    bf16x8s ra = *(const bf16x8s*)srcA;
    bf16x8s rb = *(const bf16x8s*)srcB;
    f32x4 acc[2][2] = {};
    for (int ks = 0; ks < 12; ++ks) {
        *(bf16x8s*)(&As[(row * 4 + sw) * 8]) = ra;
        *(bf16x8s*)(&Bs[(row * 4 + sw) * 8]) = rb;
        __syncthreads();
        if (ks < 11) {   // issue next-step loads; complete under MFMA
            ra = *(const bf16x8s*)(srcA + (ks + 1) * 32);
            rb = *(const bf16x8s*)(srcB + (ks + 1) * 32);
        }
        bf16x8s a[2], b[2];
        #pragma unroll
        for (int mi = 0; mi < 2; ++mi) {
            int r = wm * 32 + mi * 16 + lm;
            a[mi] = *(const bf16x8s*)(&As[(r * 4 + swz4(r, g)) * 8]);
        }
        #pragma unroll
        for (int nj = 0; nj < 2; ++nj) {
            int r = wn * 32 + nj * 16 + lm;
            b[nj] = *(const bf16x8s*)(&Bs[(r * 4 + swz4(r, g)) * 8]);
        }
        #pragma unroll
        for (int mi = 0; mi < 2; ++mi)
            #pragma unroll
            for (int nj = 0; nj < 2; ++nj)
                acc[mi][nj] = __builtin_amdgcn_mfma_f32_16x16x32_bf16(a[mi], b[nj], acc[mi][nj], 0, 0, 0);
        __syncthreads();
    }
    #pragma unroll
    for (int mi = 0; mi < 2; ++mi)
        #pragma unroll
        for (int nj = 0; nj < 2; ++nj) {
            int j = j0 + wn * 32 + nj * 16 + lm;
            #pragma unroll
            for (int qq = 0; qq < 4; ++qq) {
                int i = i0 + wm * 32 + mi * 16 + g * 4 + qq;
                part[((size_t)kb * HH_ + i) * DD_ + j] = acc[mi][nj][qq];
            }
        }
}

// ============ L3: reductions + broadcast + zeros (float4) ============
// f4 regions of out: [0,32768) W1d; [32768,32896) b1d; [32896,41088) W2d;
// [41088,41104) b2d. Threads: W1d direct; b1/W2d one thread per i4.
__global__ void k_tail(const float* __restrict__ part, const float* __restrict__ pb1,
                       const float* __restrict__ phd, float* __restrict__ out) {
    const int gid = blockIdx.x * 256 + threadIdx.x;
    const int HD4 = 32768;
    f32x4* out4 = (f32x4*)out;
    if (gid < HD4) {
        f32x4 sv = {};
        #pragma unroll
        for (int kb = 0; kb < 16; ++kb)
            sv += *(const f32x4*)(&part[(size_t)kb * 131072 + gid * 4]);
        out4[gid] = sv;
    } else if (gid < HD4 + 128) {
        const int i4 = gid - HD4;
        f32x4 sv = {};
        for (int k2 = 0; k2 < 64; ++k2)
            sv += *(const f32x4*)(&pb1[k2 * HH_ + i4 * 4]);
        out4[HD4 + i4] = sv;
    } else if (gid < HD4 + 256) {
        const int i4 = gid - HD4 - 128;
        f32x4 sv = {};
        for (int k2 = 0; k2 < 64; ++k2)
            sv += *(const f32x4*)(&phd[k2 * HH_ + i4 * 4]);
        #pragma unroll 8
        for (int o = 0; o < OO_; ++o)
            out4[HD4 + 128 + o * 128 + i4] = sv;
    } else if (gid < HD4 + 272) {
        f32x4 z = {};
        out4[41088 + gid - HD4 - 256] = z;
    }
}

extern "C" void kernel_launch(void* const* d_in, const int* in_sizes, int n_in,
                              void* d_out, int out_size, void* d_ws, size_t ws_size,
                              hipStream_t stream) {
    const float* x  = (const float*)d_in[0];
    const float* W1 = (const float*)d_in[1];
    const float* b1 = (const float*)d_in[2];
    const float* W2 = (const float*)d_in[3];
    // d_in[4] = b2 (unused: b2 Jacobians cancel)
    const int* ap = (const int*)d_in[5];
    const int* pI = (const int*)d_in[6];
    const int* an = (const int*)d_in[7];
    const int* nI = (const int*)d_in[8];
    float* out = (float*)d_out;
    float* ws = (float*)d_ws;

    // workspace (float units)
    float* part = ws;                         // 16*131072 = 2097152
    short* Mt   = (short*)(ws + 2097152);     // 512*6144 shorts = 1572864 floats
    short* Xt   = (short*)(ws + 3670016);     // 256*6144 shorts =  786432 floats
    float* pb1  = ws + 4456448;               // 64*512 = 32768
    float* phd  = ws + 4489216;               // 64*512 = 32768

    k_mega<<<dim3(640), dim3(256), 0, stream>>>(x, W1, b1, W2, ap, pI, an, nI,
                                                Mt, Xt, pb1, phd);
    k_gemm2<<<dim3(4, 8, 16), dim3(256), 0, stream>>>(Mt, Xt, part);
    k_tail<<<dim3(130), dim3(256), 0, stream>>>(part, pb1, phd, out);
}